// Round 12
// baseline (390.726 us; speedup 1.0000x reference)
//
#include <hip/hip_runtime.h>

#define DEVI __device__ __forceinline__

typedef __attribute__((ext_vector_type(8))) short short8;
typedef __attribute__((ext_vector_type(4))) short short4v;
typedef __attribute__((ext_vector_type(4))) float f32x4;
typedef unsigned short u16;
typedef unsigned int u32;

DEVI float b2f(u16 u) { u32 x = ((u32)u) << 16; return __builtin_bit_cast(float, x); }
DEVI u16 f2b(float f) {
    u32 u = __builtin_bit_cast(u32, f);
    u32 r = u + 0x7FFFu + ((u >> 16) & 1u);   // RNE
    return (u16)(r >> 16);
}
// fast ELU: exp(v)-1 instead of expm1f; abs err ~1e-7, fine for bf16 pipeline
DEVI float eluf(float v) { return v > 0.f ? v : __expf(v) - 1.f; }

DEVI void gl16(const void* g, void* l) {
    __builtin_amdgcn_global_load_lds(
        (const __attribute__((address_space(1))) u32*)g,
        (__attribute__((address_space(3))) u32*)l, 16, 0, 0);
}

// ---------------- fused prep: convert + wct + 5x tc256 + tc(i1T) + tc(i2T) + hist ----------------
__global__ void k_prep(const float* __restrict__ api, u16* __restrict__ e16,
                       const float* __restrict__ w_m1a, u16* __restrict__ wct,
                       const float* __restrict__ w1b, const float* __restrict__ w2a,
                       const float* __restrict__ w2b, const float* __restrict__ wa,
                       const float* __restrict__ wb,
                       u16* __restrict__ t1b, u16* __restrict__ t2a, u16* __restrict__ t2b,
                       u16* __restrict__ ta, u16* __restrict__ tb,
                       const float* __restrict__ w_inc1, u16* __restrict__ i1T,
                       const float* __restrict__ w_inc2, u16* __restrict__ i2T,
                       const int* __restrict__ ei, int* __restrict__ hist) {
    __shared__ float tile[32][33];
    const int b = blockIdx.x, tid = threadIdx.x;
    const int E = 320000;

    if (b < 625) {                                   // convert api -> e16 (1.28e6 elems)
        int base = (b * 256 + tid) * 8;
        float4 a = *(const float4*)(api + base);
        float4 c = *(const float4*)(api + base + 4);
        short8 o;
        o[0] = (short)f2b(a.x); o[1] = (short)f2b(a.y);
        o[2] = (short)f2b(a.z); o[3] = (short)f2b(a.w);
        o[4] = (short)f2b(c.x); o[5] = (short)f2b(c.y);
        o[6] = (short)f2b(c.z); o[7] = (short)f2b(c.w);
        *(short8*)(e16 + base) = o;
    } else if (b < 881) {                            // WcT from w_m1a (65536 elems)
        int t = (b - 625) * 256 + tid;
        int k = t & 127, j = t >> 7;
        float v;
        if (j < 256) v = w_m1a[k * 256 + j] + w_m1a[(k + 128) * 256 + j];
        else { int jj = j - 256; v = w_m1a[(k + 256) * 256 + jj] + w_m1a[(k + 384) * 256 + jj]; }
        wct[j * 128 + k] = f2b(v);
    } else if (b < 5089) {                           // transposes
        const float* w; u16* wt; int K, Nn, Nalloc, bx, by;
        if (b < 1201) {                              // 5x 256x256 (64 blocks each)
            int idx = b - 881, wi = idx >> 6, blk = idx & 63;
            switch (wi) {
                case 0: w = w1b; wt = t1b; break;
                case 1: w = w2a; wt = t2a; break;
                case 2: w = w2b; wt = t2b; break;
                case 3: w = wa;  wt = ta;  break;
                default: w = wb; wt = tb;  break;
            }
            K = 256; Nn = 256; Nalloc = 256; bx = blk & 7; by = blk >> 3;
        } else if (b < 1249) {                       // i1T: K=128, N=384 (48 blocks)
            int idx = b - 1201;
            w = w_inc1; wt = i1T; K = 128; Nn = 384; Nalloc = 384;
            bx = idx % 12; by = idx / 12;
        } else {                                     // i2T: K=384, N=10000 (3840 blocks)
            int idx = b - 1249;
            w = w_inc2; wt = i2T; K = 384; Nn = 10000; Nalloc = 10240;
            bx = idx % 320; by = idx / 320;
        }
        int tx = tid & 31, ty = tid >> 5;
        int k0 = by * 32, n0 = bx * 32;
#pragma unroll
        for (int yy = 0; yy < 4; ++yy) {
            int k = k0 + ty + yy * 8, n = n0 + tx;
            tile[ty + yy * 8][tx] = (k < K && n < Nn) ? w[(size_t)k * Nn + n] : 0.f;
        }
        __syncthreads();
#pragma unroll
        for (int yy = 0; yy < 4; ++yy) {
            int n = n0 + ty + yy * 8, k = k0 + tx;
            if (n < Nalloc && k < K) wt[(size_t)n * K + k] = f2b(tile[tx][ty + yy * 8]);
        }
    } else {                                         // hist (1250 blocks)
        int i = (b - 5089) * 256 + tid;
        if (i < E) atomicAdd(&hist[ei[E + i]], 1);
    }
}

// ---------------- counting sort: scan + scatter ----------------
__global__ void k_scan(const int* __restrict__ hist, int* __restrict__ cursor, int NB) {
    __shared__ int part[256];
    int t = threadIdx.x;
    int base = t * 40;
    int s = 0;
    for (int i = 0; i < 40; ++i) { int idx = base + i; if (idx < NB) s += hist[idx]; }
    part[t] = s;
    __syncthreads();
    if (t == 0) { int run = 0; for (int i = 0; i < 256; ++i) { int x = part[i]; part[i] = run; run += x; } }
    __syncthreads();
    int run = part[t];
    for (int i = 0; i < 40; ++i) {
        int idx = base + i;
        if (idx < NB) { int h = hist[idx]; cursor[idx] = run; run += h; }
    }
}

__global__ void k_scatter(const int* __restrict__ ei, int* __restrict__ cursor,
                          int* __restrict__ sdst, int* __restrict__ ssrc, int E) {
    int i = blockIdx.x * 256 + threadIdx.x;
    if (i >= E) return;
    int d = ei[E + i], s = ei[i];
    int pos = atomicAdd(&cursor[d], 1);
    sdst[pos] = d;
    ssrc[pos] = s;
}

// ---------------- generic bf16 GEMM (128x128): C = A @ BT^T -> bf16 ----------------
__global__ __launch_bounds__(256, 2)
void k_gemm(const u16* __restrict__ A, const u16* __restrict__ BT,
            void* __restrict__ Cv, int M, int N, int K, int lda, int ldbt, int ldc) {
    __shared__ short lsA[128 * 64];
    __shared__ short lsB[128 * 64];
    const int tid = threadIdx.x, wave = tid >> 6, lane = tid & 63;
    const int m0 = blockIdx.y * 128, n0 = blockIdx.x * 128;
    const int wm = wave >> 1, wn = wave & 1;
    const int rowA = lane >> 3, colA = (lane & 7) * 8;

    f32x4 acc[4][4] = {};

    const int kch = K >> 6;
    for (int kc = 0; kc < kch; ++kc) {
#pragma unroll
        for (int i = 0; i < 4; ++i) {
            int slot = wave * 4 + i;
            const u16* ga = A + (size_t)(m0 + slot * 8 + rowA) * lda + kc * 64 + colA;
            gl16(ga, &lsA[slot * 512]);
            const u16* gb = BT + (size_t)(n0 + slot * 8 + rowA) * ldbt + kc * 64 + colA;
            gl16(gb, &lsB[slot * 512]);
        }
        __syncthreads();
#pragma unroll
        for (int ks = 0; ks < 2; ++ks) {
            short8 a[4], b[4];
#pragma unroll
            for (int m = 0; m < 4; ++m)
                a[m] = *(const short8*)&lsA[(wm * 64 + m * 16 + (lane & 15)) * 64 + ks * 32 + (lane >> 4) * 8];
#pragma unroll
            for (int n = 0; n < 4; ++n)
                b[n] = *(const short8*)&lsB[(wn * 64 + n * 16 + (lane & 15)) * 64 + ks * 32 + (lane >> 4) * 8];
#pragma unroll
            for (int m = 0; m < 4; ++m)
#pragma unroll
                for (int n = 0; n < 4; ++n)
                    acc[m][n] = __builtin_amdgcn_mfma_f32_16x16x32_bf16(a[m], b[n], acc[m][n], 0, 0, 0);
        }
        __syncthreads();
    }

#pragma unroll
    for (int m = 0; m < 4; ++m) {
#pragma unroll
        for (int n = 0; n < 4; ++n) {
            int colg = n0 + wn * 64 + n * 16 + (lane & 15);
#pragma unroll
            for (int j = 0; j < 4; ++j) {
                int rowg = m0 + wm * 64 + m * 16 + (lane >> 4) * 4 + j;
                if (rowg < M && colg < N)
                    ((u16*)Cv)[(size_t)rowg * ldc + colg] = f2b(acc[m][n][j]);
            }
        }
    }
}

// ---------------- final GEMM v4: 256x128 tile, 8 waves, BK=32 DOUBLE-BUFFERED, ----------------
// 2 blocks/CU (48KB LDS). stage(next) issued before compute(cur), ONE barrier/step ->
// stage latency overlaps MFMA while cross-block TLP is retained (untested R4/R7 quadrant).
// Swizzle for 64B rows: chunk c ^= (row>>1)&3 (worst 2-way = free). acc[4][4]=64 regs,
// total ~110 < 128 cap at (512,4) -> no spill. NT stores; 2D sub-chunked XCD swizzle.
__global__ __launch_bounds__(512, 4)
void k_gemm2(const u16* __restrict__ A, const u16* __restrict__ BT,
             const float* __restrict__ bias, float* __restrict__ C,
             int M, int N, int K, int lda, int ldbt, int ldc) {
    __shared__ short lsA[2][256 * 32];   // 2 x 16KB
    __shared__ short lsB[2][128 * 32];   // 2 x 8KB  (48KB total)
    const int tid = threadIdx.x, wave = tid >> 6, lane = tid & 63;
    const int g = lane >> 4, l15 = lane & 15;
    const int orig = blockIdx.x;                      // 3160 = 8 * 395
    const int wg = (orig & 7) * 395 + (orig >> 3);
    const int x = wg / 395;                           // XCD chunk 0..7
    const int l = wg - x * 395;                       // 0..394
    int bxl, byl;
    if (l < 360) { int sc = l / 40, r = l - sc * 40; int q = r / 5; bxl = sc * 8 + q; byl = r - q * 5; }
    else         { int r = l - 360;                   int q = r / 5; bxl = 72 + q;     byl = r - q * 5; }
    const int bx = bxl, by = x * 5 + byl;
    const int m0 = by * 256, n0 = bx * 128;
    const int wm = wave >> 1, wn = wave & 1;          // 4 x 2 wave grid
    const int srow = lane >> 2, schk = lane & 3;      // stage: 16 rows x 4 chunks per 1KB slot

    auto stage = [&](int buf, int kc) {
#pragma unroll
        for (int i = 0; i < 2; ++i) {                 // A: 16 slots x 16 rows
            int s = wave * 2 + i;
            int row = s * 16 + srow;
            const u16* ga = A + (size_t)(m0 + row) * lda + kc * 32
                          + ((schk ^ ((row >> 1) & 3)) * 8);
            gl16(ga, &lsA[buf][s * 512]);
        }
        {                                             // B: 8 slots x 16 rows
            int s = wave;
            int row = s * 16 + srow;
            const u16* gb = BT + (size_t)(n0 + row) * ldbt + kc * 32
                          + ((schk ^ ((row >> 1) & 3)) * 8);
            gl16(gb, &lsB[buf][s * 512]);
        }
    };

    f32x4 acc[4][4] = {};
    const int kch = K >> 5;                           // 12
    stage(0, 0);
    __syncthreads();
    int cur = 0;
    for (int kc = 0; kc < kch; ++kc) {
        if (kc + 1 < kch) stage(cur ^ 1, kc + 1);     // loads in flight during MFMA
        short8 a[4], b[4];
#pragma unroll
        for (int m = 0; m < 4; ++m) {
            int ar = wm * 64 + m * 16 + l15;
            a[m] = *(const short8*)&lsA[cur][ar * 32 + ((g ^ ((ar >> 1) & 3)) * 8)];
        }
#pragma unroll
        for (int n = 0; n < 4; ++n) {
            int br = wn * 64 + n * 16 + l15;
            b[n] = *(const short8*)&lsB[cur][br * 32 + ((g ^ ((br >> 1) & 3)) * 8)];
        }
        // swapped operands: lane reg j -> C[row = m*16+l15][col = n*16 + 4g + j]
#pragma unroll
        for (int m = 0; m < 4; ++m)
#pragma unroll
            for (int n = 0; n < 4; ++n)
                acc[m][n] = __builtin_amdgcn_mfma_f32_16x16x32_bf16(b[n], a[m], acc[m][n], 0, 0, 0);
        __syncthreads();                              // drains next-tile vmcnt + cur reads
        cur ^= 1;
    }

#pragma unroll
    for (int m = 0; m < 4; ++m) {
        int row = m0 + wm * 64 + m * 16 + l15;
        if (row < M) {
#pragma unroll
            for (int n = 0; n < 4; ++n) {
                int col0 = n0 + wn * 64 + n * 16 + g * 4;
                if (col0 < N) {
                    float4 bv = *(const float4*)(bias + col0);
                    f32x4 o;
                    o[0] = 1.f / (1.f + __expf(-(acc[m][n][0] + bv.x)));
                    o[1] = 1.f / (1.f + __expf(-(acc[m][n][1] + bv.y)));
                    o[2] = 1.f / (1.f + __expf(-(acc[m][n][2] + bv.z)));
                    o[3] = 1.f / (1.f + __expf(-(acc[m][n][3] + bv.w)));
                    __builtin_nontemporal_store(o, (f32x4*)(C + (size_t)row * ldc + col0));
                }
            }
        }
    }
}

// ---------------- fused node-MLP chain: agg(fp32) -> 4x(GEMM256+ELU) -> GEMM384+ReLU -> H1 ----
__global__ __launch_bounds__(256, 2)
void k_chain(const float* __restrict__ agg,
             const u16* __restrict__ w2aT, const float* __restrict__ b_m2a,
             const u16* __restrict__ w2bT, const float* __restrict__ b_m2b,
             const u16* __restrict__ waT,  const float* __restrict__ b_ma,
             const u16* __restrict__ wbT,  const float* __restrict__ b_mb,
             const u16* __restrict__ i1T,  const float* __restrict__ b_inc1,
             u16* __restrict__ H1, int M) {
    __shared__ short lsX[32 * 256];     // 16KB, [row][256 k], 16B chunks XOR row&7
    __shared__ short lsW[384 * 64];     // 48KB, [outcol][64 k]
    const int tid = threadIdx.x, wave = tid >> 6, lane = tid & 63;
    const int g = lane >> 4, l15 = lane & 15;
    const int r0 = blockIdx.x * 32;

    // stage X = bf16(agg rows), swizzled
    for (int c = tid; c < 2048; c += 256) {       // 2048 float4 groups
        int row = c >> 6, cg = c & 63;            // cg = group of 4 cols
        int grow = r0 + row;
        float4 v = (grow < M) ? *(const float4*)(agg + (size_t)grow * 256 + cg * 4)
                              : float4{0.f, 0.f, 0.f, 0.f};
        short4v o;
        o[0] = (short)f2b(v.x); o[1] = (short)f2b(v.y);
        o[2] = (short)f2b(v.z); o[3] = (short)f2b(v.w);
        *(short4v*)&lsX[row * 256 + (((cg >> 1) ^ (row & 7)) * 8 + (cg & 1) * 4)] = o;
    }

    auto do_layer = [&](const u16* WT, const float* bias) {
        f32x4 acc[2][4] = {};
        for (int kc = 0; kc < 4; ++kc) {
#pragma unroll
            for (int i = 0; i < 8; ++i) {         // stage 256x64 W (32KB)
                int slot = wave * 8 + i;
                int br = slot * 8 + (lane >> 3);
                const u16* gw = WT + (size_t)br * 256 + kc * 64 + (((lane & 7) ^ (br & 7)) * 8);
                gl16(gw, &lsW[slot * 512]);
            }
            __syncthreads();
#pragma unroll
            for (int ks = 0; ks < 2; ++ks) {
                short8 a[2], b[4];
#pragma unroll
                for (int m = 0; m < 2; ++m) {
                    int ar = m * 16 + l15;
                    a[m] = *(const short8*)&lsX[ar * 256 + (kc * 8 + ((ks * 4 + g) ^ (ar & 7))) * 8];
                }
#pragma unroll
                for (int n = 0; n < 4; ++n) {
                    int br = wave * 64 + n * 16 + l15;
                    b[n] = *(const short8*)&lsW[(br * 8 + ((ks * 4 + g) ^ (br & 7))) * 8];
                }
#pragma unroll
                for (int m = 0; m < 2; ++m)
#pragma unroll
                    for (int n = 0; n < 4; ++n)
                        acc[m][n] = __builtin_amdgcn_mfma_f32_16x16x32_bf16(b[n], a[m], acc[m][n], 0, 0, 0);
            }
            __syncthreads();
        }
        // epilogue: ELU -> X (swizzled 8B writes); next stage's barrier orders reads
#pragma unroll
        for (int m = 0; m < 2; ++m) {
#pragma unroll
            for (int n = 0; n < 4; ++n) {
                int row = m * 16 + l15;
                int col0 = wave * 64 + n * 16 + g * 4;
                float4 bv = *(const float4*)(bias + col0);
                short4v o;
                o[0] = (short)f2b(eluf(acc[m][n][0] + bv.x));
                o[1] = (short)f2b(eluf(acc[m][n][1] + bv.y));
                o[2] = (short)f2b(eluf(acc[m][n][2] + bv.z));
                o[3] = (short)f2b(eluf(acc[m][n][3] + bv.w));
                int cg = col0 >> 2;
                *(short4v*)&lsX[row * 256 + (((cg >> 1) ^ (row & 7)) * 8 + (cg & 1) * 4)] = o;
            }
        }
        __syncthreads();
    };

    do_layer(w2aT, b_m2a);
    do_layer(w2bT, b_m2b);
    do_layer(waT,  b_ma);
    do_layer(wbT,  b_mb);

    // H1 layer: A = X cols 128..255 (K=128), B = i1T (384 x 128), ReLU -> global
    f32x4 acc2[2][6] = {};
    for (int kc = 0; kc < 2; ++kc) {
#pragma unroll
        for (int i = 0; i < 12; ++i) {            // stage 384x64 W (48KB)
            int slot = wave * 12 + i;
            int br = slot * 8 + (lane >> 3);
            const u16* gw = i1T + (size_t)br * 128 + kc * 64 + (((lane & 7) ^ (br & 7)) * 8);
            gl16(gw, &lsW[slot * 512]);
        }
        __syncthreads();
#pragma unroll
        for (int ks = 0; ks < 2; ++ks) {
            short8 a[2], b[6];
#pragma unroll
            for (int m = 0; m < 2; ++m) {
                int ar = m * 16 + l15;
                a[m] = *(const short8*)&lsX[ar * 256 + (16 + kc * 8 + ((ks * 4 + g) ^ (ar & 7))) * 8];
            }
#pragma unroll
            for (int n = 0; n < 6; ++n) {
                int br = wave * 96 + n * 16 + l15;
                b[n] = *(const short8*)&lsW[(br * 8 + ((ks * 4 + g) ^ (br & 7))) * 8];
            }
#pragma unroll
            for (int m = 0; m < 2; ++m)
#pragma unroll
                for (int n = 0; n < 6; ++n)
                    acc2[m][n] = __builtin_amdgcn_mfma_f32_16x16x32_bf16(b[n], a[m], acc2[m][n], 0, 0, 0);
        }
        __syncthreads();
    }
#pragma unroll
    for (int m = 0; m < 2; ++m) {
        int grow = r0 + m * 16 + l15;
        if (grow < M) {
#pragma unroll
            for (int n = 0; n < 6; ++n) {
                int col0 = wave * 96 + n * 16 + g * 4;
                float4 bv = *(const float4*)(b_inc1 + col0);
                float v0 = acc2[m][n][0] + bv.x, v1 = acc2[m][n][1] + bv.y;
                float v2 = acc2[m][n][2] + bv.z, v3 = acc2[m][n][3] + bv.w;
                short4v o;
                o[0] = (short)f2b(v0 > 0.f ? v0 : 0.f);
                o[1] = (short)f2b(v1 > 0.f ? v1 : 0.f);
                o[2] = (short)f2b(v2 > 0.f ? v2 : 0.f);
                o[3] = (short)f2b(v3 > 0.f ? v3 : 0.f);
                *(short4v*)&H1[(size_t)grow * 384 + col0] = o;
            }
        }
    }
}

// ---------------- edge kernel v6 (R9-proven): sorted edges, T14 dual prefetch, ----------------
// hoisted a-frags, barrier-free per-wave epilogue. 2 blocks/CU — acc needs ~212 regs
// total (128 acc + frags + addressing); (256,3)'s 168-cap SPILLS (R10 lesson).
__global__ __launch_bounds__(256, 2)
void k_edge(const u16* __restrict__ P, const int* __restrict__ sdst,
            const int* __restrict__ ssrc, const float* __restrict__ b1,
            const u16* __restrict__ W2T, const float* __restrict__ b2,
            float* __restrict__ agg) {
    __shared__ __align__(16) char smem[49152];   // A:[0,16K) B:[16K,48K) O:[0,34816)
    __shared__ int dstl[128];
    __shared__ int srcl[128];
    short* lsA = (short*)smem;
    short* lsB = (short*)(smem + 16384);
    float* lsO = (float*)smem;                   // 128 x 68 fp32
    const int tid = threadIdx.x, wave = tid >> 6, lane = tid & 63;
    const int eb = blockIdx.x * 128;
    const int g = lane >> 4, l15 = lane & 15;

    if (tid < 128) srcl[tid] = ssrc[eb + tid];
    else dstl[tid - 128] = sdst[eb + (tid - 128)];
    __syncthreads();

    short8 rpd[4], rps[4];
    auto loadA = [&](int kc) {
#pragma unroll
        for (int it = 0; it < 4; ++it) {
            int chunk = it * 256 + tid;
            int r = chunk >> 3, cc = chunk & 7;
            int col = kc * 64 + cc * 8;
            rpd[it] = *(const short8*)(P + (size_t)dstl[r] * 512 + col);
            rps[it] = *(const short8*)(P + (size_t)srcl[r] * 512 + 256 + col);
        }
    };

    loadA(0);
    f32x4 acc[4][2][4] = {};

    for (int kc = 0; kc < 4; ++kc) {
#pragma unroll
        for (int it = 0; it < 4; ++it) {
            int chunk = it * 256 + tid;
            int r = chunk >> 3, cc = chunk & 7;
            int col = kc * 64 + cc * 8;
            float bv[8];
            *(float4*)&bv[0] = *(const float4*)(b1 + col);
            *(float4*)&bv[4] = *(const float4*)(b1 + col + 4);
            short8 o;
#pragma unroll
            for (int jj = 0; jj < 8; ++jj) {
                float v = b2f((u16)rpd[it][jj]) + b2f((u16)rps[it][jj]) + bv[jj];
                o[jj] = (short)f2b(eluf(v));
            }
            int ccs = cc ^ (r & 7);
            *(short8*)&lsA[(r * 8 + ccs) * 8] = o;
        }
#pragma unroll
        for (int i = 0; i < 8; ++i) {
            int br = (wave * 8 + i) * 8 + (lane >> 3);
            const u16* gb = W2T + (size_t)br * 256 + kc * 64 + (((lane & 7) ^ (br & 7)) * 8);
            gl16(gb, lsB + (wave * 8 + i) * 512);
        }
        __syncthreads();
        if (kc < 3) loadA(kc + 1);               // gather latency hides under MFMA
        short8 af[2][2];
#pragma unroll
        for (int ks = 0; ks < 2; ++ks)
#pragma unroll
            for (int m = 0; m < 2; ++m) {
                int ar = wave * 32 + m * 16 + l15;
                af[ks][m] = *(const short8*)&lsA[(ar * 8 + ((ks * 4 + g) ^ (ar & 7))) * 8];
            }
#pragma unroll
        for (int nq = 0; nq < 4; ++nq) {
#pragma unroll
            for (int ks = 0; ks < 2; ++ks) {
                short8 b[4];
#pragma unroll
                for (int n = 0; n < 4; ++n) {
                    int br = nq * 64 + n * 16 + l15;
                    b[n] = *(const short8*)&lsB[(br * 8 + ((ks * 4 + g) ^ (br & 7))) * 8];
                }
#pragma unroll
                for (int m = 0; m < 2; ++m)
#pragma unroll
                    for (int n = 0; n < 4; ++n)
                        acc[nq][m][n] = __builtin_amdgcn_mfma_f32_16x16x32_bf16(af[ks][m], b[n], acc[nq][m][n], 0, 0, 0);
            }
        }
        __syncthreads();
    }

    // barrier-free epilogue: wave w writes/reads only its own lsO rows.
    const int r0w = wave * 32;
    const int dls = dstl[r0w + (lane & 31)];

#pragma unroll
    for (int nq = 0; nq < 4; ++nq) {
        float b2v[4];
#pragma unroll
        for (int n = 0; n < 4; ++n) b2v[n] = b2[nq * 64 + n * 16 + l15];
#pragma unroll
        for (int m = 0; m < 2; ++m)
#pragma unroll
            for (int n = 0; n < 4; ++n)
#pragma unroll
                for (int j = 0; j < 4; ++j) {
                    int row = r0w + m * 16 + g * 4 + j;
                    lsO[row * 68 + n * 16 + l15] = eluf(acc[nq][m][n][j] + b2v[n]);
                }
        {
            int dprev = __builtin_amdgcn_readlane(dls, 0);
            float sum = 0.f;
#pragma unroll
            for (int i = 0; i < 32; ++i) {
                int d = __builtin_amdgcn_readlane(dls, i);   // SGPR, no LDS in chain
                float v = lsO[(r0w + i) * 68 + lane];
                if (d != dprev) {
                    atomicAdd(&agg[(size_t)dprev * 256 + nq * 64 + lane], sum);
                    sum = v; dprev = d;
                } else sum += v;
            }
            atomicAdd(&agg[(size_t)dprev * 256 + nq * 64 + lane], sum);
        }
    }
}

extern "C" void kernel_launch(void* const* d_in, const int* in_sizes, int n_in,
                              void* d_out, int out_size, void* d_ws, size_t ws_size,
                              hipStream_t stream) {
    const float* api    = (const float*)d_in[0];
    const int*   ei     = (const int*)d_in[2];
    const float* w_m1a  = (const float*)d_in[7];
    const float* b_m1a  = (const float*)d_in[8];
    const float* w_m1b  = (const float*)d_in[9];
    const float* b_m1b  = (const float*)d_in[10];
    const float* w_m2a  = (const float*)d_in[11];
    const float* b_m2a  = (const float*)d_in[12];
    const float* w_m2b  = (const float*)d_in[13];
    const float* b_m2b  = (const float*)d_in[14];
    const float* w_ma   = (const float*)d_in[15];
    const float* b_ma   = (const float*)d_in[16];
    const float* w_mb   = (const float*)d_in[17];
    const float* b_mb   = (const float*)d_in[18];
    const float* w_inc1 = (const float*)d_in[19];
    const float* b_inc1 = (const float*)d_in[20];
    const float* w_inc2 = (const float*)d_in[21];
    const float* b_inc2 = (const float*)d_in[22];

    const int N = 10000, C = 128, E = 320000, Mp = 10112;   // Mp = 79*128
    const int Mp2 = 10240;                                   // 40*256 (final-GEMM padding)

    char* w = (char*)d_ws;
    size_t off = 0;
    auto alloc = [&](size_t bytes) { void* p = w + off; off += (bytes + 255) & ~(size_t)255; return p; };
    u16* e16   = (u16*)alloc((size_t)Mp * 128 * 2);
    u16* WcT   = (u16*)alloc(512 * 128 * 2);
    u16* P     = (u16*)alloc((size_t)Mp * 512 * 2);
    u16* w1bT  = (u16*)alloc(256 * 256 * 2);
    u16* w2aT  = (u16*)alloc(256 * 256 * 2);
    u16* w2bT  = (u16*)alloc(256 * 256 * 2);
    u16* waT   = (u16*)alloc(256 * 256 * 2);
    u16* wbT   = (u16*)alloc(256 * 256 * 2);
    u16* i1T   = (u16*)alloc(384 * 128 * 2);
    u16* i2T   = (u16*)alloc((size_t)Mp2 * 384 * 2);
    float* agg = (float*)alloc((size_t)N * 256 * 4);
    u16* H1    = (u16*)alloc((size_t)Mp2 * 384 * 2);
    int* hist  = (int*)alloc((size_t)N * 4);
    int* cursor= (int*)alloc((size_t)N * 4);
    int* sdst  = (int*)alloc((size_t)E * 4);
    int* ssrc  = (int*)alloc((size_t)E * 4);
    (void)ws_size; (void)in_sizes; (void)n_in; (void)out_size;

    hipMemsetAsync(hist, 0, (size_t)N * 4, stream);
    hipMemsetAsync(agg, 0, (size_t)N * 256 * 4, stream);

    // fused prep: convert + wct + 7 transposes + hist  (6339 blocks)
    k_prep<<<6339, 256, 0, stream>>>(api, e16, w_m1a, WcT,
                                     w_m1b, w_m2a, w_m2b, w_ma, w_mb,
                                     w1bT, w2aT, w2bT, waT, wbT,
                                     w_inc1, i1T, w_inc2, i2T, ei, hist);
    k_scan<<<1, 256, 0, stream>>>(hist, cursor, N);
    k_scatter<<<1250, 256, 0, stream>>>(ei, cursor, sdst, ssrc, E);

    // P = e @ Wc  (node projections [pd | ps])
    k_gemm<<<dim3(4, 79), 256, 0, stream>>>(e16, WcT, P, N, 512, 128, 128, 128, 512);
    // edge layer + segment-sum (sorted, dual-prefetch, 2 blocks/CU)
    k_edge<<<2500, 256, 0, stream>>>(P, sdst, ssrc, b_m1a, w1bT, b_m1b, agg);
    // fused node-MLP chain: agg -> 4x(GEMM+ELU) -> GEMM384+ReLU -> H1
    k_chain<<<313, 256, 0, stream>>>(agg, w2aT, b_m2a, w2bT, b_m2b,
                                     waT, b_ma, wbT, b_mb, i1T, b_inc1, H1, N);
    // final: sigmoid(H1 @ w_inc2 + b_inc2) -> d_out fp32 (256x128 dbuf-BK32, 79x40 grid)
    k_gemm2<<<3160, 512, 0, stream>>>(H1, i2T, b_inc2, (float*)d_out,
                                      N, 10000, 384, 384, 384, 10000);
}

// Round 13
// 381.790 us; speedup vs baseline: 1.0234x; 1.0234x over previous
//
#include <hip/hip_runtime.h>

#define DEVI __device__ __forceinline__

typedef __attribute__((ext_vector_type(8))) short short8;
typedef __attribute__((ext_vector_type(4))) short short4v;
typedef __attribute__((ext_vector_type(4))) float f32x4;
typedef unsigned short u16;
typedef unsigned int u32;

DEVI float b2f(u16 u) { u32 x = ((u32)u) << 16; return __builtin_bit_cast(float, x); }
DEVI u16 f2b(float f) {
    u32 u = __builtin_bit_cast(u32, f);
    u32 r = u + 0x7FFFu + ((u >> 16) & 1u);   // RNE
    return (u16)(r >> 16);
}
// fast ELU: exp(v)-1 instead of expm1f; abs err ~1e-7, fine for bf16 pipeline
DEVI float eluf(float v) { return v > 0.f ? v : __expf(v) - 1.f; }

DEVI void gl16(const void* g, void* l) {
    __builtin_amdgcn_global_load_lds(
        (const __attribute__((address_space(1))) u32*)g,
        (__attribute__((address_space(3))) u32*)l, 16, 0, 0);
}

// ---------------- fused prep: convert + wct + 5x tc256 + tc(i1T) + tc(i2T) + hist ----------------
__global__ void k_prep(const float* __restrict__ api, u16* __restrict__ e16,
                       const float* __restrict__ w_m1a, u16* __restrict__ wct,
                       const float* __restrict__ w1b, const float* __restrict__ w2a,
                       const float* __restrict__ w2b, const float* __restrict__ wa,
                       const float* __restrict__ wb,
                       u16* __restrict__ t1b, u16* __restrict__ t2a, u16* __restrict__ t2b,
                       u16* __restrict__ ta, u16* __restrict__ tb,
                       const float* __restrict__ w_inc1, u16* __restrict__ i1T,
                       const float* __restrict__ w_inc2, u16* __restrict__ i2T,
                       const int* __restrict__ ei, int* __restrict__ hist) {
    __shared__ float tile[32][33];
    const int b = blockIdx.x, tid = threadIdx.x;
    const int E = 320000;

    if (b < 625) {                                   // convert api -> e16 (1.28e6 elems)
        int base = (b * 256 + tid) * 8;
        float4 a = *(const float4*)(api + base);
        float4 c = *(const float4*)(api + base + 4);
        short8 o;
        o[0] = (short)f2b(a.x); o[1] = (short)f2b(a.y);
        o[2] = (short)f2b(a.z); o[3] = (short)f2b(a.w);
        o[4] = (short)f2b(c.x); o[5] = (short)f2b(c.y);
        o[6] = (short)f2b(c.z); o[7] = (short)f2b(c.w);
        *(short8*)(e16 + base) = o;
    } else if (b < 881) {                            // WcT from w_m1a (65536 elems)
        int t = (b - 625) * 256 + tid;
        int k = t & 127, j = t >> 7;
        float v;
        if (j < 256) v = w_m1a[k * 256 + j] + w_m1a[(k + 128) * 256 + j];
        else { int jj = j - 256; v = w_m1a[(k + 256) * 256 + jj] + w_m1a[(k + 384) * 256 + jj]; }
        wct[j * 128 + k] = f2b(v);
    } else if (b < 5089) {                           // transposes
        const float* w; u16* wt; int K, Nn, Nalloc, bx, by;
        if (b < 1201) {                              // 5x 256x256 (64 blocks each)
            int idx = b - 881, wi = idx >> 6, blk = idx & 63;
            switch (wi) {
                case 0: w = w1b; wt = t1b; break;
                case 1: w = w2a; wt = t2a; break;
                case 2: w = w2b; wt = t2b; break;
                case 3: w = wa;  wt = ta;  break;
                default: w = wb; wt = tb;  break;
            }
            K = 256; Nn = 256; Nalloc = 256; bx = blk & 7; by = blk >> 3;
        } else if (b < 1249) {                       // i1T: K=128, N=384 (48 blocks)
            int idx = b - 1201;
            w = w_inc1; wt = i1T; K = 128; Nn = 384; Nalloc = 384;
            bx = idx % 12; by = idx / 12;
        } else {                                     // i2T: K=384, N=10000 (3840 blocks)
            int idx = b - 1249;
            w = w_inc2; wt = i2T; K = 384; Nn = 10000; Nalloc = 10240;
            bx = idx % 320; by = idx / 320;
        }
        int tx = tid & 31, ty = tid >> 5;
        int k0 = by * 32, n0 = bx * 32;
#pragma unroll
        for (int yy = 0; yy < 4; ++yy) {
            int k = k0 + ty + yy * 8, n = n0 + tx;
            tile[ty + yy * 8][tx] = (k < K && n < Nn) ? w[(size_t)k * Nn + n] : 0.f;
        }
        __syncthreads();
#pragma unroll
        for (int yy = 0; yy < 4; ++yy) {
            int n = n0 + ty + yy * 8, k = k0 + tx;
            if (n < Nalloc && k < K) wt[(size_t)n * K + k] = f2b(tile[tx][ty + yy * 8]);
        }
    } else {                                         // hist (1250 blocks)
        int i = (b - 5089) * 256 + tid;
        if (i < E) atomicAdd(&hist[ei[E + i]], 1);
    }
}

// ---------------- counting sort: scan + scatter ----------------
__global__ void k_scan(const int* __restrict__ hist, int* __restrict__ cursor, int NB) {
    __shared__ int part[256];
    int t = threadIdx.x;
    int base = t * 40;
    int s = 0;
    for (int i = 0; i < 40; ++i) { int idx = base + i; if (idx < NB) s += hist[idx]; }
    part[t] = s;
    __syncthreads();
    if (t == 0) { int run = 0; for (int i = 0; i < 256; ++i) { int x = part[i]; part[i] = run; run += x; } }
    __syncthreads();
    int run = part[t];
    for (int i = 0; i < 40; ++i) {
        int idx = base + i;
        if (idx < NB) { int h = hist[idx]; cursor[idx] = run; run += h; }
    }
}

__global__ void k_scatter(const int* __restrict__ ei, int* __restrict__ cursor,
                          int* __restrict__ sdst, int* __restrict__ ssrc, int E) {
    int i = blockIdx.x * 256 + threadIdx.x;
    if (i >= E) return;
    int d = ei[E + i], s = ei[i];
    int pos = atomicAdd(&cursor[d], 1);
    sdst[pos] = d;
    ssrc[pos] = s;
}

// ---------------- generic bf16 GEMM (128x128): C = A @ BT^T -> bf16 ----------------
__global__ __launch_bounds__(256, 2)
void k_gemm(const u16* __restrict__ A, const u16* __restrict__ BT,
            void* __restrict__ Cv, int M, int N, int K, int lda, int ldbt, int ldc) {
    __shared__ short lsA[128 * 64];
    __shared__ short lsB[128 * 64];
    const int tid = threadIdx.x, wave = tid >> 6, lane = tid & 63;
    const int m0 = blockIdx.y * 128, n0 = blockIdx.x * 128;
    const int wm = wave >> 1, wn = wave & 1;
    const int rowA = lane >> 3, colA = (lane & 7) * 8;

    f32x4 acc[4][4] = {};

    const int kch = K >> 6;
    for (int kc = 0; kc < kch; ++kc) {
#pragma unroll
        for (int i = 0; i < 4; ++i) {
            int slot = wave * 4 + i;
            const u16* ga = A + (size_t)(m0 + slot * 8 + rowA) * lda + kc * 64 + colA;
            gl16(ga, &lsA[slot * 512]);
            const u16* gb = BT + (size_t)(n0 + slot * 8 + rowA) * ldbt + kc * 64 + colA;
            gl16(gb, &lsB[slot * 512]);
        }
        __syncthreads();
#pragma unroll
        for (int ks = 0; ks < 2; ++ks) {
            short8 a[4], b[4];
#pragma unroll
            for (int m = 0; m < 4; ++m)
                a[m] = *(const short8*)&lsA[(wm * 64 + m * 16 + (lane & 15)) * 64 + ks * 32 + (lane >> 4) * 8];
#pragma unroll
            for (int n = 0; n < 4; ++n)
                b[n] = *(const short8*)&lsB[(wn * 64 + n * 16 + (lane & 15)) * 64 + ks * 32 + (lane >> 4) * 8];
#pragma unroll
            for (int m = 0; m < 4; ++m)
#pragma unroll
                for (int n = 0; n < 4; ++n)
                    acc[m][n] = __builtin_amdgcn_mfma_f32_16x16x32_bf16(a[m], b[n], acc[m][n], 0, 0, 0);
        }
        __syncthreads();
    }

#pragma unroll
    for (int m = 0; m < 4; ++m) {
#pragma unroll
        for (int n = 0; n < 4; ++n) {
            int colg = n0 + wn * 64 + n * 16 + (lane & 15);
#pragma unroll
            for (int j = 0; j < 4; ++j) {
                int rowg = m0 + wm * 64 + m * 16 + (lane >> 4) * 4 + j;
                if (rowg < M && colg < N)
                    ((u16*)Cv)[(size_t)rowg * ldc + colg] = f2b(acc[m][n][j]);
            }
        }
    }
}

// ---------------- final GEMM (R11-proven): 256x128 tile, 8 waves, single-buffer BK=64, ----------------
// 2 blocks/CU. Bijective chunked XCD swizzle + 2D sub-chunking (8bx x 5by); NT stores.
// R12 lesson: BK=32 dbuf regressed — at 2 blocks/CU the barrier drain is already
// TLP-covered; fewer, bigger steps win.
__global__ __launch_bounds__(512, 4)
void k_gemm2(const u16* __restrict__ A, const u16* __restrict__ BT,
             const float* __restrict__ bias, float* __restrict__ C,
             int M, int N, int K, int lda, int ldbt, int ldc) {
    __shared__ short lsA[256 * 64];   // 32KB
    __shared__ short lsB[128 * 64];   // 16KB
    const int tid = threadIdx.x, wave = tid >> 6, lane = tid & 63;
    const int g = lane >> 4, l15 = lane & 15;
    const int orig = blockIdx.x;                      // 3160 = 8 * 395
    const int wg = (orig & 7) * 395 + (orig >> 3);
    const int x = wg / 395;                           // XCD chunk 0..7
    const int l = wg - x * 395;                       // 0..394
    int bxl, byl;
    if (l < 360) { int sc = l / 40, r = l - sc * 40; int q = r / 5; bxl = sc * 8 + q; byl = r - q * 5; }
    else         { int r = l - 360;                   int q = r / 5; bxl = 72 + q;     byl = r - q * 5; }
    const int bx = bxl, by = x * 5 + byl;
    const int m0 = by * 256, n0 = bx * 128;
    const int wm = wave >> 1, wn = wave & 1;          // 4 x 2 wave grid
    const int sr = lane >> 3, sc2 = lane & 7;

    f32x4 acc[4][4] = {};
    const int kch = K >> 6;                           // 6
    for (int kc = 0; kc < kch; ++kc) {
#pragma unroll
        for (int i = 0; i < 4; ++i) {
            int s = wave * 4 + i;                     // 32 slots x 8 rows
            int br = s * 8 + sr;
            const u16* ga = A + (size_t)(m0 + br) * lda + kc * 64 + ((sc2 ^ (br & 7)) * 8);
            gl16(ga, &lsA[s * 512]);
        }
#pragma unroll
        for (int i = 0; i < 2; ++i) {
            int s = wave * 2 + i;                     // 16 slots
            int br = s * 8 + sr;
            const u16* gb = BT + (size_t)(n0 + br) * ldbt + kc * 64 + ((sc2 ^ (br & 7)) * 8);
            gl16(gb, &lsB[s * 512]);
        }
        __syncthreads();
#pragma unroll
        for (int ks = 0; ks < 2; ++ks) {
            short8 a[4], b[4];
#pragma unroll
            for (int m = 0; m < 4; ++m) {
                int ar = wm * 64 + m * 16 + l15;
                a[m] = *(const short8*)&lsA[(ar * 8 + ((ks * 4 + g) ^ (ar & 7))) * 8];
            }
#pragma unroll
            for (int n = 0; n < 4; ++n) {
                int br = wn * 64 + n * 16 + l15;
                b[n] = *(const short8*)&lsB[(br * 8 + ((ks * 4 + g) ^ (br & 7))) * 8];
            }
            // swapped operands: lane reg j -> C[row = m*16+l15][col = n*16 + 4g + j]
#pragma unroll
            for (int m = 0; m < 4; ++m)
#pragma unroll
                for (int n = 0; n < 4; ++n)
                    acc[m][n] = __builtin_amdgcn_mfma_f32_16x16x32_bf16(b[n], a[m], acc[m][n], 0, 0, 0);
        }
        __syncthreads();
    }

#pragma unroll
    for (int m = 0; m < 4; ++m) {
        int row = m0 + wm * 64 + m * 16 + l15;
        if (row < M) {
#pragma unroll
            for (int n = 0; n < 4; ++n) {
                int col0 = n0 + wn * 64 + n * 16 + g * 4;
                if (col0 < N) {
                    float4 bv = *(const float4*)(bias + col0);
                    f32x4 o;
                    o[0] = 1.f / (1.f + __expf(-(acc[m][n][0] + bv.x)));
                    o[1] = 1.f / (1.f + __expf(-(acc[m][n][1] + bv.y)));
                    o[2] = 1.f / (1.f + __expf(-(acc[m][n][2] + bv.z)));
                    o[3] = 1.f / (1.f + __expf(-(acc[m][n][3] + bv.w)));
                    __builtin_nontemporal_store(o, (f32x4*)(C + (size_t)row * ldc + col0));
                }
            }
        }
    }
}

// ---------------- fused node-MLP chain: agg(fp32) -> 4x(GEMM256+ELU) -> GEMM384+ReLU -> H1 ----
__global__ __launch_bounds__(256, 2)
void k_chain(const float* __restrict__ agg,
             const u16* __restrict__ w2aT, const float* __restrict__ b_m2a,
             const u16* __restrict__ w2bT, const float* __restrict__ b_m2b,
             const u16* __restrict__ waT,  const float* __restrict__ b_ma,
             const u16* __restrict__ wbT,  const float* __restrict__ b_mb,
             const u16* __restrict__ i1T,  const float* __restrict__ b_inc1,
             u16* __restrict__ H1, int M) {
    __shared__ short lsX[32 * 256];     // 16KB, [row][256 k], 16B chunks XOR row&7
    __shared__ short lsW[384 * 64];     // 48KB, [outcol][64 k]
    const int tid = threadIdx.x, wave = tid >> 6, lane = tid & 63;
    const int g = lane >> 4, l15 = lane & 15;
    const int r0 = blockIdx.x * 32;

    // stage X = bf16(agg rows), swizzled
    for (int c = tid; c < 2048; c += 256) {       // 2048 float4 groups
        int row = c >> 6, cg = c & 63;            // cg = group of 4 cols
        int grow = r0 + row;
        float4 v = (grow < M) ? *(const float4*)(agg + (size_t)grow * 256 + cg * 4)
                              : float4{0.f, 0.f, 0.f, 0.f};
        short4v o;
        o[0] = (short)f2b(v.x); o[1] = (short)f2b(v.y);
        o[2] = (short)f2b(v.z); o[3] = (short)f2b(v.w);
        *(short4v*)&lsX[row * 256 + (((cg >> 1) ^ (row & 7)) * 8 + (cg & 1) * 4)] = o;
    }

    auto do_layer = [&](const u16* WT, const float* bias) {
        f32x4 acc[2][4] = {};
        for (int kc = 0; kc < 4; ++kc) {
#pragma unroll
            for (int i = 0; i < 8; ++i) {         // stage 256x64 W (32KB)
                int slot = wave * 8 + i;
                int br = slot * 8 + (lane >> 3);
                const u16* gw = WT + (size_t)br * 256 + kc * 64 + (((lane & 7) ^ (br & 7)) * 8);
                gl16(gw, &lsW[slot * 512]);
            }
            __syncthreads();
#pragma unroll
            for (int ks = 0; ks < 2; ++ks) {
                short8 a[2], b[4];
#pragma unroll
                for (int m = 0; m < 2; ++m) {
                    int ar = m * 16 + l15;
                    a[m] = *(const short8*)&lsX[ar * 256 + (kc * 8 + ((ks * 4 + g) ^ (ar & 7))) * 8];
                }
#pragma unroll
                for (int n = 0; n < 4; ++n) {
                    int br = wave * 64 + n * 16 + l15;
                    b[n] = *(const short8*)&lsW[(br * 8 + ((ks * 4 + g) ^ (br & 7))) * 8];
                }
#pragma unroll
                for (int m = 0; m < 2; ++m)
#pragma unroll
                    for (int n = 0; n < 4; ++n)
                        acc[m][n] = __builtin_amdgcn_mfma_f32_16x16x32_bf16(b[n], a[m], acc[m][n], 0, 0, 0);
            }
            __syncthreads();
        }
        // epilogue: ELU -> X (swizzled 8B writes); next stage's barrier orders reads
#pragma unroll
        for (int m = 0; m < 2; ++m) {
#pragma unroll
            for (int n = 0; n < 4; ++n) {
                int row = m * 16 + l15;
                int col0 = wave * 64 + n * 16 + g * 4;
                float4 bv = *(const float4*)(bias + col0);
                short4v o;
                o[0] = (short)f2b(eluf(acc[m][n][0] + bv.x));
                o[1] = (short)f2b(eluf(acc[m][n][1] + bv.y));
                o[2] = (short)f2b(eluf(acc[m][n][2] + bv.z));
                o[3] = (short)f2b(eluf(acc[m][n][3] + bv.w));
                int cg = col0 >> 2;
                *(short4v*)&lsX[row * 256 + (((cg >> 1) ^ (row & 7)) * 8 + (cg & 1) * 4)] = o;
            }
        }
        __syncthreads();
    };

    do_layer(w2aT, b_m2a);
    do_layer(w2bT, b_m2b);
    do_layer(waT,  b_ma);
    do_layer(wbT,  b_mb);

    // H1 layer: A = X cols 128..255 (K=128), B = i1T (384 x 128), ReLU -> global
    f32x4 acc2[2][6] = {};
    for (int kc = 0; kc < 2; ++kc) {
#pragma unroll
        for (int i = 0; i < 12; ++i) {            // stage 384x64 W (48KB)
            int slot = wave * 12 + i;
            int br = slot * 8 + (lane >> 3);
            const u16* gw = i1T + (size_t)br * 128 + kc * 64 + (((lane & 7) ^ (br & 7)) * 8);
            gl16(gw, &lsW[slot * 512]);
        }
        __syncthreads();
#pragma unroll
        for (int ks = 0; ks < 2; ++ks) {
            short8 a[2], b[6];
#pragma unroll
            for (int m = 0; m < 2; ++m) {
                int ar = m * 16 + l15;
                a[m] = *(const short8*)&lsX[ar * 256 + (16 + kc * 8 + ((ks * 4 + g) ^ (ar & 7))) * 8];
            }
#pragma unroll
            for (int n = 0; n < 6; ++n) {
                int br = wave * 96 + n * 16 + l15;
                b[n] = *(const short8*)&lsW[(br * 8 + ((ks * 4 + g) ^ (br & 7))) * 8];
            }
#pragma unroll
            for (int m = 0; m < 2; ++m)
#pragma unroll
                for (int n = 0; n < 6; ++n)
                    acc2[m][n] = __builtin_amdgcn_mfma_f32_16x16x32_bf16(b[n], a[m], acc2[m][n], 0, 0, 0);
        }
        __syncthreads();
    }
#pragma unroll
    for (int m = 0; m < 2; ++m) {
        int grow = r0 + m * 16 + l15;
        if (grow < M) {
#pragma unroll
            for (int n = 0; n < 6; ++n) {
                int col0 = wave * 96 + n * 16 + g * 4;
                float4 bv = *(const float4*)(b_inc1 + col0);
                float v0 = acc2[m][n][0] + bv.x, v1 = acc2[m][n][1] + bv.y;
                float v2 = acc2[m][n][2] + bv.z, v3 = acc2[m][n][3] + bv.w;
                short4v o;
                o[0] = (short)f2b(v0 > 0.f ? v0 : 0.f);
                o[1] = (short)f2b(v1 > 0.f ? v1 : 0.f);
                o[2] = (short)f2b(v2 > 0.f ? v2 : 0.f);
                o[3] = (short)f2b(v3 > 0.f ? v3 : 0.f);
                *(short4v*)&H1[(size_t)grow * 384 + col0] = o;
            }
        }
    }
}

// ---------------- edge kernel v6 (R9-proven): sorted edges, T14 dual prefetch, ----------------
// hoisted a-frags, barrier-free per-wave epilogue. 2 blocks/CU — acc needs ~212 regs
// total (128 acc + frags + addressing); (256,3)'s 168-cap SPILLS (R10 lesson).
__global__ __launch_bounds__(256, 2)
void k_edge(const u16* __restrict__ P, const int* __restrict__ sdst,
            const int* __restrict__ ssrc, const float* __restrict__ b1,
            const u16* __restrict__ W2T, const float* __restrict__ b2,
            float* __restrict__ agg) {
    __shared__ __align__(16) char smem[49152];   // A:[0,16K) B:[16K,48K) O:[0,34816)
    __shared__ int dstl[128];
    __shared__ int srcl[128];
    short* lsA = (short*)smem;
    short* lsB = (short*)(smem + 16384);
    float* lsO = (float*)smem;                   // 128 x 68 fp32
    const int tid = threadIdx.x, wave = tid >> 6, lane = tid & 63;
    const int eb = blockIdx.x * 128;
    const int g = lane >> 4, l15 = lane & 15;

    if (tid < 128) srcl[tid] = ssrc[eb + tid];
    else dstl[tid - 128] = sdst[eb + (tid - 128)];
    __syncthreads();

    short8 rpd[4], rps[4];
    auto loadA = [&](int kc) {
#pragma unroll
        for (int it = 0; it < 4; ++it) {
            int chunk = it * 256 + tid;
            int r = chunk >> 3, cc = chunk & 7;
            int col = kc * 64 + cc * 8;
            rpd[it] = *(const short8*)(P + (size_t)dstl[r] * 512 + col);
            rps[it] = *(const short8*)(P + (size_t)srcl[r] * 512 + 256 + col);
        }
    };

    loadA(0);
    f32x4 acc[4][2][4] = {};

    for (int kc = 0; kc < 4; ++kc) {
#pragma unroll
        for (int it = 0; it < 4; ++it) {
            int chunk = it * 256 + tid;
            int r = chunk >> 3, cc = chunk & 7;
            int col = kc * 64 + cc * 8;
            float bv[8];
            *(float4*)&bv[0] = *(const float4*)(b1 + col);
            *(float4*)&bv[4] = *(const float4*)(b1 + col + 4);
            short8 o;
#pragma unroll
            for (int jj = 0; jj < 8; ++jj) {
                float v = b2f((u16)rpd[it][jj]) + b2f((u16)rps[it][jj]) + bv[jj];
                o[jj] = (short)f2b(eluf(v));
            }
            int ccs = cc ^ (r & 7);
            *(short8*)&lsA[(r * 8 + ccs) * 8] = o;
        }
#pragma unroll
        for (int i = 0; i < 8; ++i) {
            int br = (wave * 8 + i) * 8 + (lane >> 3);
            const u16* gb = W2T + (size_t)br * 256 + kc * 64 + (((lane & 7) ^ (br & 7)) * 8);
            gl16(gb, lsB + (wave * 8 + i) * 512);
        }
        __syncthreads();
        if (kc < 3) loadA(kc + 1);               // gather latency hides under MFMA
        short8 af[2][2];
#pragma unroll
        for (int ks = 0; ks < 2; ++ks)
#pragma unroll
            for (int m = 0; m < 2; ++m) {
                int ar = wave * 32 + m * 16 + l15;
                af[ks][m] = *(const short8*)&lsA[(ar * 8 + ((ks * 4 + g) ^ (ar & 7))) * 8];
            }
#pragma unroll
        for (int nq = 0; nq < 4; ++nq) {
#pragma unroll
            for (int ks = 0; ks < 2; ++ks) {
                short8 b[4];
#pragma unroll
                for (int n = 0; n < 4; ++n) {
                    int br = nq * 64 + n * 16 + l15;
                    b[n] = *(const short8*)&lsB[(br * 8 + ((ks * 4 + g) ^ (br & 7))) * 8];
                }
#pragma unroll
                for (int m = 0; m < 2; ++m)
#pragma unroll
                    for (int n = 0; n < 4; ++n)
                        acc[nq][m][n] = __builtin_amdgcn_mfma_f32_16x16x32_bf16(af[ks][m], b[n], acc[nq][m][n], 0, 0, 0);
            }
        }
        __syncthreads();
    }

    // barrier-free epilogue: wave w writes/reads only its own lsO rows.
    const int r0w = wave * 32;
    const int dls = dstl[r0w + (lane & 31)];

#pragma unroll
    for (int nq = 0; nq < 4; ++nq) {
        float b2v[4];
#pragma unroll
        for (int n = 0; n < 4; ++n) b2v[n] = b2[nq * 64 + n * 16 + l15];
#pragma unroll
        for (int m = 0; m < 2; ++m)
#pragma unroll
            for (int n = 0; n < 4; ++n)
#pragma unroll
                for (int j = 0; j < 4; ++j) {
                    int row = r0w + m * 16 + g * 4 + j;
                    lsO[row * 68 + n * 16 + l15] = eluf(acc[nq][m][n][j] + b2v[n]);
                }
        {
            int dprev = __builtin_amdgcn_readlane(dls, 0);
            float sum = 0.f;
#pragma unroll
            for (int i = 0; i < 32; ++i) {
                int d = __builtin_amdgcn_readlane(dls, i);   // SGPR, no LDS in chain
                float v = lsO[(r0w + i) * 68 + lane];
                if (d != dprev) {
                    atomicAdd(&agg[(size_t)dprev * 256 + nq * 64 + lane], sum);
                    sum = v; dprev = d;
                } else sum += v;
            }
            atomicAdd(&agg[(size_t)dprev * 256 + nq * 64 + lane], sum);
        }
    }
}

extern "C" void kernel_launch(void* const* d_in, const int* in_sizes, int n_in,
                              void* d_out, int out_size, void* d_ws, size_t ws_size,
                              hipStream_t stream) {
    const float* api    = (const float*)d_in[0];
    const int*   ei     = (const int*)d_in[2];
    const float* w_m1a  = (const float*)d_in[7];
    const float* b_m1a  = (const float*)d_in[8];
    const float* w_m1b  = (const float*)d_in[9];
    const float* b_m1b  = (const float*)d_in[10];
    const float* w_m2a  = (const float*)d_in[11];
    const float* b_m2a  = (const float*)d_in[12];
    const float* w_m2b  = (const float*)d_in[13];
    const float* b_m2b  = (const float*)d_in[14];
    const float* w_ma   = (const float*)d_in[15];
    const float* b_ma   = (const float*)d_in[16];
    const float* w_mb   = (const float*)d_in[17];
    const float* b_mb   = (const float*)d_in[18];
    const float* w_inc1 = (const float*)d_in[19];
    const float* b_inc1 = (const float*)d_in[20];
    const float* w_inc2 = (const float*)d_in[21];
    const float* b_inc2 = (const float*)d_in[22];

    const int N = 10000, C = 128, E = 320000, Mp = 10112;   // Mp = 79*128
    const int Mp2 = 10240;                                   // 40*256 (final-GEMM padding)

    char* w = (char*)d_ws;
    size_t off = 0;
    auto alloc = [&](size_t bytes) { void* p = w + off; off += (bytes + 255) & ~(size_t)255; return p; };
    u16* e16   = (u16*)alloc((size_t)Mp * 128 * 2);
    u16* WcT   = (u16*)alloc(512 * 128 * 2);
    u16* P     = (u16*)alloc((size_t)Mp * 512 * 2);
    u16* w1bT  = (u16*)alloc(256 * 256 * 2);
    u16* w2aT  = (u16*)alloc(256 * 256 * 2);
    u16* w2bT  = (u16*)alloc(256 * 256 * 2);
    u16* waT   = (u16*)alloc(256 * 256 * 2);
    u16* wbT   = (u16*)alloc(256 * 256 * 2);
    u16* i1T   = (u16*)alloc(384 * 128 * 2);
    u16* i2T   = (u16*)alloc((size_t)Mp2 * 384 * 2);
    float* agg = (float*)alloc((size_t)N * 256 * 4);
    u16* H1    = (u16*)alloc((size_t)Mp2 * 384 * 2);
    int* hist  = (int*)alloc((size_t)N * 4);
    int* cursor= (int*)alloc((size_t)N * 4);
    int* sdst  = (int*)alloc((size_t)E * 4);
    int* ssrc  = (int*)alloc((size_t)E * 4);
    (void)ws_size; (void)in_sizes; (void)n_in; (void)out_size;

    hipMemsetAsync(hist, 0, (size_t)N * 4, stream);
    hipMemsetAsync(agg, 0, (size_t)N * 256 * 4, stream);

    // fused prep: convert + wct + 7 transposes + hist  (6339 blocks)
    k_prep<<<6339, 256, 0, stream>>>(api, e16, w_m1a, WcT,
                                     w_m1b, w_m2a, w_m2b, w_ma, w_mb,
                                     w1bT, w2aT, w2bT, waT, wbT,
                                     w_inc1, i1T, w_inc2, i2T, ei, hist);
    k_scan<<<1, 256, 0, stream>>>(hist, cursor, N);
    k_scatter<<<1250, 256, 0, stream>>>(ei, cursor, sdst, ssrc, E);

    // P = e @ Wc  (node projections [pd | ps])
    k_gemm<<<dim3(4, 79), 256, 0, stream>>>(e16, WcT, P, N, 512, 128, 128, 128, 512);
    // edge layer + segment-sum (sorted, dual-prefetch, 2 blocks/CU)
    k_edge<<<2500, 256, 0, stream>>>(P, sdst, ssrc, b_m1a, w1bT, b_m1b, agg);
    // fused node-MLP chain: agg -> 4x(GEMM+ELU) -> GEMM384+ReLU -> H1
    k_chain<<<313, 256, 0, stream>>>(agg, w2aT, b_m2a, w2bT, b_m2b,
                                     waT, b_ma, wbT, b_mb, i1T, b_inc1, H1, N);
    // final: sigmoid(H1 @ w_inc2 + b_inc2) -> d_out fp32 (256x128 single-buf, 79x40 grid)
    k_gemm2<<<3160, 512, 0, stream>>>(H1, i2T, b_inc2, (float*)d_out,
                                      N, 10000, 384, 384, 384, 10000);
}